// Round 6
// baseline (181.257 us; speedup 1.0000x reference)
//
#include <hip/hip_runtime.h>
#include <hip/hip_bf16.h>

// Problem: B=2, S=2048, D=768, H=12, HD=64. fp32 in/out, bf16 MFMA inside.
// r27 = r26 (key-split) + V IN REGISTERS from a TILED global layout:
// repack_v emits per-64-key tiles [nt][k8][l16][8] so a wave's 8 V B-frags
// are 8 coalesced 1KB global_load_dwordx4 (lane off = quad*256B + l16*16B).
// V is register-prefetched ONE TILE AHEAD, loads issued AFTER PV consumes
// the regs (WAR) -> they drain at the barrier's vmcnt(0); no mid-iter vmcnt
// wait, K-glds16 overlap preserved (fixes r25's failure mode). Deletes
// 8 ds_read_b128 + 2 glds16 per lane/iter (half the LDS pipe load -> TA/L1;
// V tile 8KB, 4 waves same addrs -> L1-served). LDS 32768->16384.
// Win ledger: r4 LDS staging+dbuf, r5 xor-swizzle, r10 coalesced repack,
// r15 GEMM2 64x64, r18 GEMM1 128x96, r22 swapped-QK^T in-register P,
// r24 glds16 pre-swizzled staging + l-on-MFMA, r26 key-split (attn 59.7->55.2,
// occupancy 24->31%; combine +6us ate the gain).
// Failure ledger (do not revisit): r7 mfma16, r8 wave-split, r11 32x32 MFMA,
// r12 BK=64, r9/r13/r14 math micro-opts, r16 GEMM1 64x128, r20 GEMM2 dbuf,
// r23 2-wave/32q blocks, r25 V-direct-global consumed mid-iter (vmcnt
// in-order drained K prefetch, 59.7->108us).
#define B_ 2
#define S_ 2048
#define D_ 768
#define H_ 12
#define HD_ 64
#define EXP2C_ 0.1803368801111244f  // SCALE * log2(e), folded into Q

typedef __attribute__((ext_vector_type(8))) short bf16x8;
typedef __attribute__((ext_vector_type(8))) unsigned short u16x8;
typedef __attribute__((ext_vector_type(4))) float f32x4;
typedef __attribute__((ext_vector_type(4))) unsigned int u32x4;

static __device__ __forceinline__ unsigned short f2bf(float x) {
    union { float f; unsigned u; } v; v.f = x;
    unsigned r = (v.u + 0x7FFFu + ((v.u >> 16) & 1u)) >> 16;  // RNE
    return (unsigned short)r;
}
static __device__ __forceinline__ float bf2f(unsigned short h) {
    union { unsigned u; float f; } v; v.u = ((unsigned)h) << 16;
    return v.f;
}
static __device__ __forceinline__ float fexp2(float x) { return __builtin_exp2f(x); }

// packed f32x2 -> bf16x2 (v_cvt_pk_bf16_f32) as raw u32; low 16 = first arg
static __device__ __forceinline__ unsigned pk_bf16(float a, float b) {
    __hip_bfloat162 pk = __float22bfloat162_rn(make_float2(a, b));
    union { __hip_bfloat162 h; unsigned u; } v; v.h = pk;
    return v.u;
}

static __device__ __forceinline__ f32x4 mfma32(bf16x8 a, bf16x8 b, f32x4 c) {
    return __builtin_amdgcn_mfma_f32_16x16x32_bf16(a, b, c, 0, 0, 0);
}

// async global->LDS, 16B/lane; LDS dest = wave-uniform base + lane*16 (m97)
typedef __attribute__((address_space(3))) unsigned int lds_u32;
typedef __attribute__((address_space(1))) const unsigned int glb_u32;
static __device__ __forceinline__ void glds16(const unsigned short* g, unsigned short* l) {
    __builtin_amdgcn_global_load_lds((glb_u32*)g, (lds_u32*)l, 16, 0, 0);
}

// ---------------------------------------------------------------------------
// Merged prep: conv x->bf16 | transpose w_qkv | transpose w_proj.
// ---------------------------------------------------------------------------
#define PREP_CONV_ 1536   // 4096*768/(256*8)
#define PREP_TQKV_ 1728   // (2304/32)*(768/32)
#define PREP_TPRJ_ 576    // (768/32)*(768/32)
__global__ __launch_bounds__(256) void prep_kernel(
    const float* __restrict__ x,      unsigned short* __restrict__ x16,
    const float* __restrict__ w_qkv,  unsigned short* __restrict__ wqkvT,
    const float* __restrict__ w_proj, unsigned short* __restrict__ wprojT)
{
    __shared__ float tile[32][33];
    const int bid = blockIdx.x, t = threadIdx.x;
    if (bid < PREP_CONV_) {
        const int i = (bid * 256 + t) * 8;
        float4 a0 = *(const float4*)(x + i);
        float4 a1 = *(const float4*)(x + i + 4);
        u16x8 s;
        s[0] = f2bf(a0.x); s[1] = f2bf(a0.y); s[2] = f2bf(a0.z); s[3] = f2bf(a0.w);
        s[4] = f2bf(a1.x); s[5] = f2bf(a1.y); s[6] = f2bf(a1.z); s[7] = f2bf(a1.w);
        *(u16x8*)(x16 + i) = s;
        return;
    }
    const float* w; unsigned short* wT; int N, bb;
    if (bid < PREP_CONV_ + PREP_TQKV_) { w = w_qkv; wT = wqkvT; N = 3 * D_; bb = bid - PREP_CONV_; }
    else                               { w = w_proj; wT = wprojT; N = D_;   bb = bid - PREP_CONV_ - PREP_TQKV_; }
    const int K = D_;
    const int nt = N / 32;
    const int n0 = (bb % nt) * 32, k0 = (bb / nt) * 32;
    const int tx = t & 31, ty = t >> 5;
#pragma unroll
    for (int i = 0; i < 4; i++)
        tile[ty + i * 8][tx] = w[(size_t)(k0 + ty + i * 8) * N + n0 + tx];
    __syncthreads();
#pragma unroll
    for (int i = 0; i < 4; i++)
        wT[(size_t)(n0 + ty + i * 8) * K + k0 + tx] = f2bf(tile[tx][ty + i * 8]);
}

// ---------------------------------------------------------------------------
// Pure-bf16 GEMM + bias: C[M][N] = A[M][K] . Bt[N][K]^T + bias[N]
// BMxBN tile, BK=32, 4 waves (each (BM/2)x(BN/2) quadrant), glds16 staging.
// Measured tile space: GEMM1 128x96 (768 blocks = 3/CU balance, r18 win);
// GEMM2 64x64 (768 blocks, r15 win).
// ---------------------------------------------------------------------------
template <int BM, int BN, bool OUT_F32>
__global__ __launch_bounds__(256) void gemm_bt_kernel(
    const unsigned short* __restrict__ A,
    const unsigned short* __restrict__ Bt,
    const float* __restrict__ bias,
    void* __restrict__ Cp,
    int M, int N, int K)
{
    __shared__ __align__(16) unsigned short As[BM][32];
    __shared__ __align__(16) unsigned short Bs[BN][32];
    constexpr int MI = BM / 32, NJ = BN / 32;   // frags per wave quadrant
    constexpr int ACH = BM * 4, BCH = BN * 4;   // 16B chunks per tile

    const int t = threadIdx.x;
    const int w = t >> 6, lane = t & 63, quad = lane >> 4, l16 = lane & 15;
    const int n0 = blockIdx.x * BN, m0 = blockIdx.y * BM;
    const int mw = (w & 1) * (BM / 2), nw = (w >> 1) * (BN / 2);

    const f32x4 z = {0.f, 0.f, 0.f, 0.f};
    f32x4 acc[MI][NJ];
#pragma unroll
    for (int i = 0; i < MI; i++)
#pragma unroll
        for (int j = 0; j < NJ; j++) acc[i][j] = z;

    for (int kk = 0; kk < K; kk += 32) {
#pragma unroll
        for (int it = 0; it < (ACH + 255) / 256; it++) {
            const int c = t + it * 256;
            if (ACH % 256 == 0 || c < ACH) {
                const int row = c >> 2, c8 = (c & 3) << 3;
                glds16(A + (size_t)(m0 + row) * K + kk + c8, &As[0][0] + c * 8);
            }
        }
#pragma unroll
        for (int it = 0; it < (BCH + 255) / 256; it++) {
            const int c = t + it * 256;
            if (BCH % 256 == 0 || c < BCH) {
                const int row = c >> 2, c8 = (c & 3) << 3;
                glds16(Bt + (size_t)(n0 + row) * K + kk + c8, &Bs[0][0] + c * 8);
            }
        }
        __syncthreads();

        bf16x8 a[MI], b[NJ];
#pragma unroll
        for (int i = 0; i < MI; i++)
            a[i] = *(const bf16x8*)(&As[mw + i * 16 + l16][quad * 8]);
#pragma unroll
        for (int j = 0; j < NJ; j++)
            b[j] = *(const bf16x8*)(&Bs[nw + j * 16 + l16][quad * 8]);
#pragma unroll
        for (int i = 0; i < MI; i++)
#pragma unroll
            for (int j = 0; j < NJ; j++)
                acc[i][j] = mfma32(a[i], b[j], acc[i][j]);
        __syncthreads();
    }

#pragma unroll
    for (int j = 0; j < NJ; j++) {
        const int col = n0 + nw + j * 16 + l16;
        const float bv = bias[col];
#pragma unroll
        for (int i = 0; i < MI; i++) {
#pragma unroll
            for (int r = 0; r < 4; r++) {
                const int row = m0 + mw + i * 16 + quad * 4 + r;
                const float v = acc[i][j][r] + bv;
                if (OUT_F32) ((float*)Cp)[(size_t)row * N + col] = v;
                else         ((unsigned short*)Cp)[(size_t)row * N + col] = f2bf(v);
            }
        }
    }
}

// ---------------------------------------------------------------------------
// Repack V (r27): LDS-tiled transpose -> TILED output layout.
// vtp element order: [bh][kt][nt][k8][l16][e] (e=0..7), value =
// V[key = kt*64 + k8*8 + e][d = nt*16 + l16]. A wave's V B-frag group
// (nt, half) is then 1KB contiguous: lane(quad,l16) at quad*128 + l16*8.
// ---------------------------------------------------------------------------
__global__ __launch_bounds__(256) void repack_v_kernel(
    const unsigned short* __restrict__ qkv,
    unsigned short* __restrict__ vtp)
{
    __shared__ unsigned short T[64][65];
    const int t = threadIdx.x;
    const int bh = blockIdx.x, st = blockIdx.y;
    const int b = bh / H_, h = bh % H_;
    const unsigned short* src =
        qkv + (size_t)(b * S_ + st * 64) * (3 * D_) + 2 * D_ + h * HD_;

#pragma unroll
    for (int it = 0; it < 2; it++) {
        const int c = t + it * 256, sr = c >> 3, g = c & 7;
        u16x8 v = *(const u16x8*)(src + (size_t)sr * (3 * D_) + g * 8);
#pragma unroll
        for (int j = 0; j < 8; j++) T[sr][g * 8 + j] = v[j];
    }
    __syncthreads();
#pragma unroll
    for (int it = 0; it < 2; it++) {
        const int c = t + it * 256, hd = c >> 3, g = c & 7;
        u16x8 v;
#pragma unroll
        for (int j = 0; j < 8; j++) v[j] = T[g * 8 + j][hd];
        const size_t off =
            ((((size_t)(bh * 32 + st) * 4 + (hd >> 4)) * 8 + g) * 16 + (hd & 15)) * 8;
        *(u16x8*)(vtp + off) = v;
    }
}

// ---------------------------------------------------------------------------
// Flash attention — r27: key-split (blockIdx.z), K via glds16+LDS (swizzled),
// V in REGISTERS from tiled layout, prefetched one tile ahead (loads issued
// after PV consumes the regs -> drain at barrier vmcnt(0), no mid-iter wait).
//
// Key-row permutation (r22, verified): A-frag row l16 of tile-slice nt reads
// Ks row rowp = (nt>>1)*32 + (l16>>2)*8 + (nt&1)*4 + (l16&3) =>
// s_acc[nt][r] = S[key=(nt>>1)*32+quad*8+(nt&1)*4+r][q=l16]; packed pa0/pa1
// are exactly the PV A-frags (k=quad*8+j over keys 0..31 / 32..63).
// Ks swizzle sK(row) = (row&3)|((row>>3&1)<<2), staged via glds16 with
// pre-swizzled global source (linear LDS dest).
// V frags: vc0[nt][j] = V[key=quad*8+j][d=nt*16+l16] at tile + nt*1024 +
// quad*128 + l16*8 (vc1: +512, keys 32..63). Coalesced 1KB per (nt,half).
// l-ones: mfma(pa, ones) -> C rows match o_acc rows; l[r] lane-local.
// ---------------------------------------------------------------------------
__global__ __launch_bounds__(256, 5) void attn_kernel(
    const unsigned short* __restrict__ qkv,  // [B*S][3*D] bf16
    const unsigned short* __restrict__ vtp,  // tiled V, 4096 elem / 64-key tile
    float* __restrict__ o_p0,                // [B*S][D] f32 partial, half 0
    float* __restrict__ o_p1,                // [B*S][D] f32 partial, half 1
    float* __restrict__ l_p)                 // [2][B*S][H] f32
{
    __shared__ __align__(16) unsigned short Ks[2][64][64];   // [key][hd], sK swizzle

    const int t = threadIdx.x;
    const int w = t >> 6, lane = t & 63, quad = lane >> 4, l16 = lane & 15;
    const int qt = blockIdx.x, bh = blockIdx.y, ks = blockIdx.z;
    const int b = bh / H_, h = bh % H_;
    const int ld = 3 * D_;  // 2304

    // Q B-frags (n=l16 -> q row, k=quad*8+j), prescaled by SCALE*log2e
    const unsigned short* qbase =
        qkv + (size_t)(b * S_ + qt * 64 + 16 * w + l16) * ld + h * HD_;
    u16x8 qr0 = *(const u16x8*)(qbase + quad * 8);
    u16x8 qr1 = *(const u16x8*)(qbase + 32 + quad * 8);
    bf16x8 qf0, qf1;
#pragma unroll
    for (int j = 0; j < 8; j++) {
        qf0[j] = (short)f2bf(bf2f(qr0[j]) * EXP2C_);
        qf1[j] = (short)f2bf(bf2f(qr1[j]) * EXP2C_);
    }

    bf16x8 ones;
#pragma unroll
    for (int j = 0; j < 8; j++) ones[j] = (short)0x3F80;  // bf16 1.0

    // key-half bases (1024 keys per half)
    const unsigned short* kbase =
        qkv + (size_t)(b * S_ + ks * 1024) * ld + D_ + h * HD_;
    // per-lane V pointer: tile base + quad*128 + l16*8 (elements)
    const unsigned short* vb =
        vtp + ((size_t)bh * 32 + ks * 16) * 4096 + quad * 128 + l16 * 8;

    // K staging source addresses (pre-swizzled global groups, glds16)
    const int c0 = t, c1 = t + 256;
    const int row0 = c0 >> 3, row1 = c1 >> 3;
    const int kg0 = (c0 & 7) ^ ((row0 & 3) | (((row0 >> 3) & 1) << 2));
    const int kg1 = (c1 & 7) ^ ((row1 & 3) | (((row1 >> 3) & 1) << 2));
    const unsigned short* kp0 = kbase + (size_t)row0 * ld + kg0 * 8;
    const unsigned short* kp1 = kbase + (size_t)row1 * ld + kg1 * 8;
    const size_t KSTEP = (size_t)64 * ld;  // elements per key tile (K side)

    const f32x4 z = {0.f, 0.f, 0.f, 0.f};
    f32x4 o_acc[4] = {z, z, z, z};
    f32x4 l_acc = z;

    // prologue: stage K tile 0; load V tile 0 into registers
    glds16(kp0, &Ks[0][0][0] + c0 * 8);
    glds16(kp1, &Ks[0][0][0] + c1 * 8);
    kp0 += KSTEP; kp1 += KSTEP;
    bf16x8 vc0[4], vc1[4];
#pragma unroll
    for (int nt = 0; nt < 4; nt++) {
        vc0[nt] = *(const bf16x8*)(vb + nt * 1024);
        vc1[nt] = *(const bf16x8*)(vb + nt * 1024 + 512);
    }
    vb += 4096;
    __syncthreads();

    const int NT = 1024 / 64;  // 16 tiles per half
    for (int kt = 0; kt < NT; kt++) {
        const int buf = kt & 1;
        const bool pre = (kt + 1 < NT);

        // K prefetch for tile kt+1 (async, drains at the barrier)
        if (pre) {
            unsigned short* kd = &Ks[buf ^ 1][0][0];
            glds16(kp0, kd + c0 * 8);
            glds16(kp1, kd + c1 * 8);
            kp0 += KSTEP; kp1 += KSTEP;
        }

        // S^T = K . Q^T from LDS: s_acc[nt][r] = S[key=perm(nt,quad*4+r)][q=l16]
        f32x4 s_acc[4] = {z, z, z, z};
#pragma unroll
        for (int nt = 0; nt < 4; nt++) {
            const int rowp = ((nt >> 1) << 5) + ((l16 >> 2) << 3) + ((nt & 1) << 2) + (l16 & 3);
            const int skr = (rowp & 3) | (((rowp >> 3) & 1) << 2);
            const unsigned short* kr = &Ks[buf][rowp][0];
            bf16x8 k0 = *(const bf16x8*)(kr + (quad ^ skr) * 8);
            bf16x8 k1 = *(const bf16x8*)(kr + ((quad ^ skr) ^ 4) * 8);
            s_acc[nt] = mfma32(k0, qf0, s_acc[nt]);
            s_acc[nt] = mfma32(k1, qf1, s_acc[nt]);
        }

        // p = exp2(s); pack to PV A-frags in registers
        f32x4 pr[4];
#pragma unroll
        for (int nt = 0; nt < 4; nt++) {
#pragma unroll
            for (int r = 0; r < 4; r++) pr[nt][r] = fexp2(s_acc[nt][r]);
        }
        union { u32x4 u; bf16x8 h; } ca, cb;
        ca.u[0] = pk_bf16(pr[0][0], pr[0][1]);
        ca.u[1] = pk_bf16(pr[0][2], pr[0][3]);
        ca.u[2] = pk_bf16(pr[1][0], pr[1][1]);
        ca.u[3] = pk_bf16(pr[1][2], pr[1][3]);
        cb.u[0] = pk_bf16(pr[2][0], pr[2][1]);
        cb.u[1] = pk_bf16(pr[2][2], pr[2][3]);
        cb.u[2] = pk_bf16(pr[3][0], pr[3][1]);
        cb.u[3] = pk_bf16(pr[3][2], pr[3][3]);
        const bf16x8 pa0 = ca.h, pa1 = cb.h;

        // l on the MFMA pipe: C rows match o_acc rows, dup over cols
        l_acc = mfma32(pa0, ones, l_acc);
        l_acc = mfma32(pa1, ones, l_acc);

        // O += P . V (register V frags loaded last iteration)
#pragma unroll
        for (int nt = 0; nt < 4; nt++) {
            o_acc[nt] = mfma32(pa0, vc0[nt], o_acc[nt]);
            o_acc[nt] = mfma32(pa1, vc1[nt], o_acc[nt]);
        }

        // V prefetch for tile kt+1 into the just-consumed registers (WAR);
        // completes at the barrier's vmcnt(0) together with the K glds16.
        if (pre) {
#pragma unroll
            for (int nt = 0; nt < 4; nt++) {
                vc0[nt] = *(const bf16x8*)(vb + nt * 1024);
                vc1[nt] = *(const bf16x8*)(vb + nt * 1024 + 512);
            }
            vb += 4096;
        }

        __syncthreads();
    }

    // epilogue: write unnormalized f32 partials + l (lane-local, no shuffles)
    float* op = ks ? o_p1 : o_p0;
    float* lp2 = l_p + (size_t)ks * (B_ * S_ * H_);
#pragma unroll
    for (int r = 0; r < 4; r++) {
        const int row = b * S_ + qt * 64 + 16 * w + quad * 4 + r;
        float* ob = op + (size_t)row * D_ + h * HD_;
#pragma unroll
        for (int nt = 0; nt < 4; nt++)
            ob[nt * 16 + l16] = o_acc[nt][r];
        if (l16 == 0) lp2[(size_t)row * H_ + h] = l_acc[r];
    }
}

// ---------------------------------------------------------------------------
// Combine: o = (o0 + o1) / (l0 + l1), emit bf16 for GEMM2.
// Each thread: 8 cols (always within one head since 64 % 8 == 0).
// ---------------------------------------------------------------------------
__global__ __launch_bounds__(256) void combine_kernel(
    const float* __restrict__ o_p0,
    const float* __restrict__ o_p1,
    const float* __restrict__ l_p,
    unsigned short* __restrict__ o)
{
    const int i = (blockIdx.x * 256 + threadIdx.x) * 8;
    const int row = i / D_, col = i - row * D_, h = col >> 6;
    const float l0 = l_p[(size_t)row * H_ + h];
    const float l1 = l_p[(size_t)(B_ * S_ * H_) + row * H_ + h];
    const float inv = 1.f / (l0 + l1);
    float4 a0 = *(const float4*)(o_p0 + i);
    float4 a1 = *(const float4*)(o_p0 + i + 4);
    float4 b0 = *(const float4*)(o_p1 + i);
    float4 b1 = *(const float4*)(o_p1 + i + 4);
    u16x8 s;
    s[0] = f2bf((a0.x + b0.x) * inv); s[1] = f2bf((a0.y + b0.y) * inv);
    s[2] = f2bf((a0.z + b0.z) * inv); s[3] = f2bf((a0.w + b0.w) * inv);
    s[4] = f2bf((a1.x + b1.x) * inv); s[5] = f2bf((a1.y + b1.y) * inv);
    s[6] = f2bf((a1.z + b1.z) * inv); s[7] = f2bf((a1.w + b1.w) * inv);
    *(u16x8*)(o + i) = s;
}

// ---------------------------------------------------------------------------
extern "C" void kernel_launch(void* const* d_in, const int* in_sizes, int n_in,
                              void* d_out, int out_size, void* d_ws, size_t ws_size,
                              hipStream_t stream) {
    const float* x      = (const float*)d_in[0];  // [4096][768]
    const float* w_qkv  = (const float*)d_in[1];  // [768][2304]
    const float* b_qkv  = (const float*)d_in[2];  // [2304]
    const float* w_proj = (const float*)d_in[3];  // [768][768]
    const float* b_proj = (const float*)d_in[4];  // [768]
    float* out = (float*)d_out;                   // [4096][768]

    // ws carve (bf16 elements). x16 ALIASES o: GEMM1 consumes x16 before
    // attn writes o. o-partial half 0 reuses d_out as f32 scratch (GEMM2
    // overwrites it at the end); half 1 + l partials appended to ws.
    unsigned short* qkv    = (unsigned short*)d_ws;                     // 9,437,184
    unsigned short* vtp    = qkv    + (size_t)(B_ * S_) * (3 * D_);     // 3,145,728
    unsigned short* o_x16  = vtp    + (size_t)(B_ * H_) * HD_ * S_;     // 3,145,728
    unsigned short* wqkvT  = o_x16  + (size_t)(B_ * S_) * D_;           // 1,769,472
    unsigned short* wprojT = wqkvT  + (size_t)D_ * (3 * D_);            //   589,824
    float* o_p1 = (float*)(wprojT + (size_t)D_ * D_);                   // 3,145,728 f32
    float* l_p  = o_p1 + (size_t)(B_ * S_) * D_;                        // 2*4096*12 f32
    float* o_p0 = out;  // d_out as scratch

    dim3 blk(256);
    prep_kernel<<<dim3(PREP_CONV_ + PREP_TQKV_ + PREP_TPRJ_), blk, 0, stream>>>(
        x, o_x16, w_qkv, wqkvT, w_proj, wprojT);
    gemm_bt_kernel<128, 96, false><<<dim3((3 * D_) / 96, (B_ * S_) / 128), blk, 0, stream>>>(
        o_x16, wqkvT, b_qkv, qkv, B_ * S_, 3 * D_, D_);
    repack_v_kernel<<<dim3(B_ * H_, S_ / 64), blk, 0, stream>>>(qkv, vtp);
    attn_kernel<<<dim3(S_ / 64, B_ * H_, 2), blk, 0, stream>>>(qkv, vtp, o_p0, o_p1, l_p);
    combine_kernel<<<dim3((B_ * S_) * D_ / (256 * 8)), blk, 0, stream>>>(
        o_p0, o_p1, l_p, o_x16);
    gemm_bt_kernel<64, 64, true><<<dim3(D_ / 64, (B_ * S_) / 64), blk, 0, stream>>>(
        o_x16, wprojT, b_proj, out, B_ * S_, D_, D_);
}